// Round 16
// baseline (500.283 us; speedup 1.0000x reference)
//
#include <hip/hip_runtime.h>

// ---------------------------------------------------------------------------
// Edge-conditioned kernel MLP, fully fused. R16: 32x32x16 MFMA (R15's halved
// LDS traffic, layouts HW-verified) at 16 waves/CU (R10's occupancy):
// 512 thr / 8 waves, wave (eg=w&3, nh=w>>2) = 32 edges x 64 features.
// LN cross-wave pair reduction via 2KB sLN folded into existing barriers.
// gemv in R10's verified position. o = c*4 + 2nh + f, i = 8q+4*l5+j.
// ---------------------------------------------------------------------------

typedef __bf16 bf16x8 __attribute__((ext_vector_type(8)));
typedef __bf16 bf16x4 __attribute__((ext_vector_type(4)));
typedef float f32x4 __attribute__((ext_vector_type(4)));
typedef float f32x16 __attribute__((ext_vector_type(16)));

#define N_EDGES 147456
#define TM 128            // edges per block
#define NTHR 512

__device__ __forceinline__ unsigned short f2bf(float f) {
    unsigned u = __float_as_uint(f);
    u = u + 0x7FFFu + ((u >> 16) & 1u);   // RNE (prep kernel only)
    return (unsigned short)(u >> 16);
}
__device__ __forceinline__ float gelu_t(float x) {
    float z = 0.7978845608f * (x + 0.044715f * x * x * x);
    return x / (1.0f + __expf(-2.0f * z));   // tanh-GELU, dev <= ~1e-3
}
__device__ __forceinline__ void gl_lds16(const unsigned short* g, unsigned char* l) {
    __builtin_amdgcn_global_load_lds(
        (const __attribute__((address_space(1))) unsigned int*)g,
        (__attribute__((address_space(3))) unsigned int*)l, 16, 0, 0);
}

// Prep (verified R7-R15, UNCHANGED): W^T bf16, PRE-SWIZZLED so linear-dest
// global_load_lds yields 16B slot s at row n holding chunk (s ^ (n&7)).
__global__ void prep_weights(const float* __restrict__ W1,
                             const float* __restrict__ W2,
                             const float* __restrict__ W3,
                             unsigned short* __restrict__ ws) {
    int t = blockIdx.x * 256 + threadIdx.x;          // 163840 total
    if (t < 16384) {
        int k = t >> 7, n = t & 127;
        ws[n * 128 + (((k >> 3) ^ (n & 7)) << 3) + (k & 7)] = f2bf(W1[t]);
    } else if (t < 32768) {
        int j = t - 16384;
        int k = j >> 7, n = j & 127;
        ws[16384 + n * 128 + (((k >> 3) ^ (n & 7)) << 3) + (k & 7)] = f2bf(W2[j]);
    } else {
        int j = t - 32768;                           // j = k*1024 + n
        int k = j >> 10, n = j & 1023;
        int tile = n >> 7, nl = n & 127;
        ws[32768 + tile * 16384 + nl * 128 + (((k >> 3) ^ (nl & 7)) << 3) + (k & 7)]
            = f2bf(W3[j]);
    }
}

__global__ __launch_bounds__(NTHR, 4)
void fused_edge_mlp(const float* __restrict__ edge, const float* __restrict__ x,
                    const float* __restrict__ b1, const float* __restrict__ g1,
                    const float* __restrict__ be1,
                    const float* __restrict__ b2, const float* __restrict__ g2,
                    const float* __restrict__ be2,
                    const float* __restrict__ b3,
                    const unsigned short* __restrict__ wsW,
                    float* __restrict__ out) {
    // sA: bf16 [128 rows][128 k], XOR-swizzled. edge->h1->h2; then W buf B.
    __shared__ __align__(16) unsigned char sA[TM * 256];       // 32 KB
    // sW: bf16 W^T tile [128 n][128 k], swizzled; W buf A.
    __shared__ __align__(16) unsigned char sW[128 * 256];      // 32 KB
    __shared__ float sLN[8][32][2];                            // 2 KB pair sums

    const int t    = threadIdx.x;
    const int lane = t & 63;
    const int w    = t >> 6;          // 8 waves
    const int e0   = blockIdx.x * TM;
    const int erow = w * 16;          // staging rows (16/wave, R10 verbatim)
    const int eg   = w & 3;           // edge group: local edges [eg*32,eg*32+32)
    const int nh   = w >> 2;          // feature half: n in [nh*64, nh*64+64)
    const int r31  = lane & 31;
    const int l5   = lane >> 5;
    const int eloc = eg * 32 + r31;   // this lane's compute edge row (local)
    const int swzl = (lane & 7) << 4; // rows used below all have row&7==lane&7
    const f32x16 zz = {0.f,0.f,0.f,0.f,0.f,0.f,0.f,0.f,
                       0.f,0.f,0.f,0.f,0.f,0.f,0.f,0.f};

    // ---- W staging: async DMA into dst (R10 verbatim) ----
    auto stageW = [&](const unsigned short* srcW, unsigned char* dst) {
#pragma unroll
        for (int i = 0; i < 4; i++) {
            int base = w * 256 + i * 64;             // 2048 x 16B chunks total
            gl_lds16(srcW + (size_t)(base + lane) * 8, dst + (size_t)base * 16);
        }
    };

    // ---- MFMA (L1/L2): C[n=64(nh half)][e=32(eg)] += W(sW)^T . h(sA), K=128
    // A: row = nh*64 + f*32 + r31, k = ks*16 + l5*8 (+j). B: row = eloc.
    auto runMM = [&](f32x16 (&acc)[2]) {
#pragma unroll
        for (int ks = 0; ks < 8; ks++) {
            int kb = (ks * 32 + l5 * 16) ^ swzl;
            bf16x8 b = *(const bf16x8*)(sA + eloc * 256 + kb);
#pragma unroll
            for (int f = 0; f < 2; f++) {
                bf16x8 a = *(const bf16x8*)(sW + (nh * 64 + f * 32 + r31) * 256 + kb);
                acc[f] = __builtin_amdgcn_mfma_f32_32x32x16_bf16(
                    a, b, (ks == 0) ? zz : acc[f], 0, 0, 0);
            }
        }
    };
    // C/D (verified R15): col(e) = lane&31, row-in-32 r = (reg&3)+8*(reg>>2)+4*l5.

    // ---- layer-3 MFMA: A from W buffer, B = h2 frags in bc regs ----
    auto runMM3 = [&](f32x16 (&acc)[2], const bf16x8 (&bc)[8],
                      const unsigned char* wbuf) {
#pragma unroll
        for (int ks = 0; ks < 8; ks++) {
            int kb = (ks * 32 + l5 * 16) ^ swzl;
#pragma unroll
            for (int f = 0; f < 2; f++) {
                bf16x8 a = *(const bf16x8*)(
                    wbuf + (nh * 64 + f * 32 + r31) * 256 + kb);
                acc[f] = __builtin_amdgcn_mfma_f32_32x32x16_bf16(
                    a, bc[ks], (ks == 0) ? zz : acc[f], 0, 0, 0);
            }
        }
    };

    // ---- LN part 1: own-half partial sums (+bias), pair-publish to sLN ----
    // Lane owns n = nh*64 + f*32 + 8q + 4*l5 + j for its edge col eloc.
    auto lnPart = [&](f32x16 (&acc)[2], const float* bb, float& s, float& s2) {
        s = 0.f; s2 = 0.f;
#pragma unroll
        for (int f = 0; f < 2; f++)
#pragma unroll
            for (int q = 0; q < 4; q++) {
                f32x4 b4 = *(const f32x4*)(bb + nh * 64 + f * 32 + q * 8 + l5 * 4);
#pragma unroll
                for (int j = 0; j < 4; j++) {
                    float v = acc[f][q * 4 + j] + b4[j];
                    s += v; s2 += v * v;
                }
            }
        s  += __shfl_xor(s, 32);                     // l5-complement rows
        s2 += __shfl_xor(s2, 32);
        if (l5 == 0) { sLN[w][r31][0] = s; sLN[w][r31][1] = s2; }
    };
    // ---- LN part 2 (after barrier): merge pair half, GELU, h -> sA ----
    auto lnFinish = [&](f32x16 (&acc)[2], const float* bb, const float* gg,
                        const float* ee, float s, float s2) {
        s  += sLN[w ^ 4][r31][0];                    // pair wave = nh flip
        s2 += sLN[w ^ 4][r31][1];
        float mean = s * (1.0f / 128.0f);
        float rsv  = rsqrtf(s2 * (1.0f / 128.0f) - mean * mean + 1e-5f);
#pragma unroll
        for (int f = 0; f < 2; f++)
#pragma unroll
            for (int q = 0; q < 4; q++) {
                f32x4 b4 = *(const f32x4*)(bb + nh * 64 + f * 32 + q * 8 + l5 * 4);
                f32x4 g4 = *(const f32x4*)(gg + nh * 64 + f * 32 + q * 8 + l5 * 4);
                f32x4 e4 = *(const f32x4*)(ee + nh * 64 + f * 32 + q * 8 + l5 * 4);
                bf16x4 u;
#pragma unroll
                for (int j = 0; j < 4; j++) {
                    float v = acc[f][q * 4 + j] + b4[j];
                    float fv = (v - mean) * rsv * g4[j] + e4[j];
                    u[j] = (__bf16)gelu_t(fv);       // v_cvt_pk_bf16_f32 (RNE)
                }
                // byte = 2n = nh*128 + f*64 + q*16 + l5*8
                *(bf16x4*)(sA + eloc * 256 +
                           ((nh * 128 + f * 64 + q * 16 + l5 * 8) ^ swzl)) = u;
            }
    };

    // ---- layer-3 GEMV: o = c*4 + 2nh + f, i = 8q + 4*l5 + j ----
    f32x4 xv[4];                      // xv[q][j] = x[eloc][8q + 4*l5 + j]
    float vout[4][2];                 // [c&3][f], lane keeps c with c>>2==l5
    auto gemv = [&](f32x16 (&acc)[2], int c) {       // c compile-time const
#pragma unroll
        for (int f = 0; f < 2; f++) {
            float p = 0.f;
#pragma unroll
            for (int q = 0; q < 4; q++)
#pragma unroll
                for (int j = 0; j < 4; j++)
                    p += acc[f][q * 4 + j] * xv[q][j];
            p += __shfl_xor(p, 32);                  // other i-half
            if ((c >> 2) == l5) vout[c & 3][f] += p; // folds at compile time
        }
    };

    // ================= prologue =================
    stageW(wsW, sW);                                 // W1 DMA (overlaps below)
#pragma unroll
    for (int i = 0; i < 4; i++) {                    // edge -> sA (R10 verbatim)
        int c = lane + i * 64;                       // 256 chunks of 8 floats
        int r = erow + (c >> 4), kg = c & 15;
        const float* src = edge + (size_t)(e0 + r) * 128 + kg * 8;
        float4 v0 = *(const float4*)src, v1 = *(const float4*)(src + 4);
        bf16x8 u;
        u[0] = (__bf16)v0.x; u[1] = (__bf16)v0.y; u[2] = (__bf16)v0.z; u[3] = (__bf16)v0.w;
        u[4] = (__bf16)v1.x; u[5] = (__bf16)v1.y; u[6] = (__bf16)v1.z; u[7] = (__bf16)v1.w;
        *(bf16x8*)(sA + r * 256 + ((kg * 16) ^ ((r & 7) << 4))) = u;
    }
#pragma unroll
    for (int q = 0; q < 4; q++)
        xv[q] = *(const f32x4*)(x + (size_t)(e0 + eloc) * 32 + q * 8 + l5 * 4);
    __syncthreads();                                 // W1 in LDS

    f32x16 acc[2];
    float s, s2;

    // ================= layer 1 =================
    runMM(acc);                       // reads sW(W1) + sA(edge)
    lnPart(acc, b1, s, s2);           // partials -> sLN
    __syncthreads();                  // (a) sW free, sLN visible
    stageW(wsW + 16384, sW);          // W2 DMA (overlaps lnFinish VALU)
    lnFinish(acc, b1, g1, be1, s, s2);// h1 -> sA (pair-disjoint bytes)
    __syncthreads();                  // (b) W2 ready, h1 visible

    // ================= layer 2 =================
    runMM(acc);
    lnPart(acc, b2, s, s2);
    __syncthreads();                  // (c)
    stageW(wsW + 32768, sW);          // W3 chunk 0 DMA
    lnFinish(acc, b2, g2, be2, s, s2);// h2 -> sA
    __syncthreads();                  // (d) W3c0 ready, h2 visible

    // ---- cache h2 B-frags (own eg, full K); init vout with b3 . x ----
    bf16x8 bc[8];
#pragma unroll
    for (int ks = 0; ks < 8; ks++)
        bc[ks] = *(const bf16x8*)(sA + eloc * 256 + ((ks * 32 + l5 * 16) ^ swzl));
#pragma unroll
    for (int c = 0; c < 8; c++)
#pragma unroll
        for (int f = 0; f < 2; f++) {
            float p = 0.f;
#pragma unroll
            for (int q = 0; q < 4; q++) {
                f32x4 b4 = *(const f32x4*)(
                    b3 + c * 128 + nh * 64 + f * 32 + q * 8 + l5 * 4);
#pragma unroll
                for (int j = 0; j < 4; j++) p += b4[j] * xv[q][j];
            }
            p += __shfl_xor(p, 32);
            if ((c >> 2) == l5) vout[c & 3][f] = p;
        }
    __syncthreads();                  // (e) bc reads done -> sA free
    stageW(wsW + 32768 + 16384, sA);  // W3 chunk 1 DMA -> sA

    // ================= layer 3: 8 chunks, ping-pong sW/sA =================
#pragma unroll
    for (int c = 0; c < 8; c++) {
        runMM3(acc, bc, (c & 1) ? sA : sW);   // read current buffer
        gemv(acc, c);                         // R10 position (R14: moving hurts)
        if (c < 7) {
            __syncthreads();          // buf(c&1) reads done; DMA(c+1) drained
            if (c < 6)                // DMA c+2 into the buffer just freed
                stageW(wsW + 32768 + (size_t)(c + 2) * 16384,
                       (c & 1) ? sA : sW);
        }
    }

    // ================= epilogue: float2 stores =================
    {
        size_t e = (size_t)(e0 + eloc);
#pragma unroll
        for (int cb = 0; cb < 4; cb++) {             // chunk c = cb + 4*l5
            float2 pv = {vout[cb][0], vout[cb][1]};
            *(float2*)(out + e * 32 + (cb + 4 * l5) * 4 + 2 * nh) = pv;
        }
    }
}

extern "C" void kernel_launch(void* const* d_in, const int* in_sizes, int n_in,
                              void* d_out, int out_size, void* d_ws, size_t ws_size,
                              hipStream_t stream) {
    const float* x    = (const float*)d_in[0];
    const float* edge = (const float*)d_in[1];
    const float* W1   = (const float*)d_in[2];
    const float* b1   = (const float*)d_in[3];
    const float* g1   = (const float*)d_in[4];
    const float* be1  = (const float*)d_in[5];
    const float* W2   = (const float*)d_in[6];
    const float* b2   = (const float*)d_in[7];
    const float* g2   = (const float*)d_in[8];
    const float* be2  = (const float*)d_in[9];
    const float* W3   = (const float*)d_in[10];
    const float* b3   = (const float*)d_in[11];
    unsigned short* wsW = (unsigned short*)d_ws;     // 320 KB pre-swizzled W^T bf16
    float* outp = (float*)d_out;

    prep_weights<<<640, 256, 0, stream>>>(W1, W2, W3, wsW);
    fused_edge_mlp<<<N_EDGES / TM, NTHR, 0, stream>>>(
        edge, x, b1, g1, be1, b2, g2, be2, b3, wsW, outp);
}

// Round 17
// 141.863 us; speedup vs baseline: 3.5265x; 3.5265x over previous
//
#include <hip/hip_runtime.h>

// ---------------------------------------------------------------------------
// Edge-conditioned kernel MLP, fully fused. R17 = R16 (verified correct:
// 32x32x16 MFMA pair-split, wave = 32 edges x 64 features, LN pair-reduce)
// with the spill fixed:
//   - __launch_bounds__(512,3): combined VGPR+AGPR cap 170 (was 128 -> spill)
//   - register diet: vout[] and b3-init pass removed; gemv folds b3 per chunk
//     and the owner half-wave stores float2 directly (L2 absorbs partials).
// Goal: allocation <= 128 combined -> 2 blocks/CU at runtime.
// ---------------------------------------------------------------------------

typedef __bf16 bf16x8 __attribute__((ext_vector_type(8)));
typedef __bf16 bf16x4 __attribute__((ext_vector_type(4)));
typedef float f32x4 __attribute__((ext_vector_type(4)));
typedef float f32x16 __attribute__((ext_vector_type(16)));

#define N_EDGES 147456
#define TM 128            // edges per block
#define NTHR 512

__device__ __forceinline__ unsigned short f2bf(float f) {
    unsigned u = __float_as_uint(f);
    u = u + 0x7FFFu + ((u >> 16) & 1u);   // RNE (prep kernel only)
    return (unsigned short)(u >> 16);
}
__device__ __forceinline__ float gelu_t(float x) {
    float z = 0.7978845608f * (x + 0.044715f * x * x * x);
    return x / (1.0f + __expf(-2.0f * z));   // tanh-GELU, dev <= ~1e-3
}
__device__ __forceinline__ void gl_lds16(const unsigned short* g, unsigned char* l) {
    __builtin_amdgcn_global_load_lds(
        (const __attribute__((address_space(1))) unsigned int*)g,
        (__attribute__((address_space(3))) unsigned int*)l, 16, 0, 0);
}

// Prep (verified R7-R16, UNCHANGED): W^T bf16, PRE-SWIZZLED so linear-dest
// global_load_lds yields 16B slot s at row n holding chunk (s ^ (n&7)).
__global__ void prep_weights(const float* __restrict__ W1,
                             const float* __restrict__ W2,
                             const float* __restrict__ W3,
                             unsigned short* __restrict__ ws) {
    int t = blockIdx.x * 256 + threadIdx.x;          // 163840 total
    if (t < 16384) {
        int k = t >> 7, n = t & 127;
        ws[n * 128 + (((k >> 3) ^ (n & 7)) << 3) + (k & 7)] = f2bf(W1[t]);
    } else if (t < 32768) {
        int j = t - 16384;
        int k = j >> 7, n = j & 127;
        ws[16384 + n * 128 + (((k >> 3) ^ (n & 7)) << 3) + (k & 7)] = f2bf(W2[j]);
    } else {
        int j = t - 32768;                           // j = k*1024 + n
        int k = j >> 10, n = j & 1023;
        int tile = n >> 7, nl = n & 127;
        ws[32768 + tile * 16384 + nl * 128 + (((k >> 3) ^ (nl & 7)) << 3) + (k & 7)]
            = f2bf(W3[j]);
    }
}

__global__ __launch_bounds__(NTHR, 3)
void fused_edge_mlp(const float* __restrict__ edge, const float* __restrict__ x,
                    const float* __restrict__ b1, const float* __restrict__ g1,
                    const float* __restrict__ be1,
                    const float* __restrict__ b2, const float* __restrict__ g2,
                    const float* __restrict__ be2,
                    const float* __restrict__ b3,
                    const unsigned short* __restrict__ wsW,
                    float* __restrict__ out) {
    // sA: bf16 [128 rows][128 k], XOR-swizzled. edge->h1->h2; then W buf B.
    __shared__ __align__(16) unsigned char sA[TM * 256];       // 32 KB
    // sW: bf16 W^T tile [128 n][128 k], swizzled; W buf A.
    __shared__ __align__(16) unsigned char sW[128 * 256];      // 32 KB
    __shared__ float sLN[8][32][2];                            // 2 KB pair sums

    const int t    = threadIdx.x;
    const int lane = t & 63;
    const int w    = t >> 6;          // 8 waves
    const int e0   = blockIdx.x * TM;
    const int erow = w * 16;          // staging rows (16/wave, R10 verbatim)
    const int eg   = w & 3;           // edge group: local edges [eg*32,eg*32+32)
    const int nh   = w >> 2;          // feature half: n in [nh*64, nh*64+64)
    const int r31  = lane & 31;
    const int l5   = lane >> 5;
    const int eloc = eg * 32 + r31;   // this lane's compute edge row (local)
    const int swzl = (lane & 7) << 4; // rows used below all have row&7==lane&7
    const f32x16 zz = {0.f,0.f,0.f,0.f,0.f,0.f,0.f,0.f,
                       0.f,0.f,0.f,0.f,0.f,0.f,0.f,0.f};

    // ---- W staging: async DMA into dst (R10 verbatim) ----
    auto stageW = [&](const unsigned short* srcW, unsigned char* dst) {
#pragma unroll
        for (int i = 0; i < 4; i++) {
            int base = w * 256 + i * 64;             // 2048 x 16B chunks total
            gl_lds16(srcW + (size_t)(base + lane) * 8, dst + (size_t)base * 16);
        }
    };

    // ---- MFMA (L1/L2): C[n=64(nh half)][e=32(eg)] += W(sW)^T . h(sA), K=128
    auto runMM = [&](f32x16 (&acc)[2]) {
#pragma unroll
        for (int ks = 0; ks < 8; ks++) {
            int kb = (ks * 32 + l5 * 16) ^ swzl;
            bf16x8 b = *(const bf16x8*)(sA + eloc * 256 + kb);
#pragma unroll
            for (int f = 0; f < 2; f++) {
                bf16x8 a = *(const bf16x8*)(sW + (nh * 64 + f * 32 + r31) * 256 + kb);
                acc[f] = __builtin_amdgcn_mfma_f32_32x32x16_bf16(
                    a, b, (ks == 0) ? zz : acc[f], 0, 0, 0);
            }
        }
    };
    // C/D (verified R15/R16): col(e)=lane&31, r-in-32 = (reg&3)+8*(reg>>2)+4*l5.

    // ---- layer-3 MFMA: A from W buffer, B = h2 frags in bc regs ----
    auto runMM3 = [&](f32x16 (&acc)[2], const bf16x8 (&bc)[8],
                      const unsigned char* wbuf) {
#pragma unroll
        for (int ks = 0; ks < 8; ks++) {
            int kb = (ks * 32 + l5 * 16) ^ swzl;
#pragma unroll
            for (int f = 0; f < 2; f++) {
                bf16x8 a = *(const bf16x8*)(
                    wbuf + (nh * 64 + f * 32 + r31) * 256 + kb);
                acc[f] = __builtin_amdgcn_mfma_f32_32x32x16_bf16(
                    a, bc[ks], (ks == 0) ? zz : acc[f], 0, 0, 0);
            }
        }
    };

    // ---- LN part 1: own-half partial sums (+bias), pair-publish to sLN ----
    auto lnPart = [&](f32x16 (&acc)[2], const float* bb, float& s, float& s2) {
        s = 0.f; s2 = 0.f;
#pragma unroll
        for (int f = 0; f < 2; f++)
#pragma unroll
            for (int q = 0; q < 4; q++) {
                f32x4 b4 = *(const f32x4*)(bb + nh * 64 + f * 32 + q * 8 + l5 * 4);
#pragma unroll
                for (int j = 0; j < 4; j++) {
                    float v = acc[f][q * 4 + j] + b4[j];
                    s += v; s2 += v * v;
                }
            }
        s  += __shfl_xor(s, 32);                     // l5-complement rows
        s2 += __shfl_xor(s2, 32);
        if (l5 == 0) { sLN[w][r31][0] = s; sLN[w][r31][1] = s2; }
    };
    // ---- LN part 2 (after barrier): merge pair half, GELU, h -> sA ----
    auto lnFinish = [&](f32x16 (&acc)[2], const float* bb, const float* gg,
                        const float* ee, float s, float s2) {
        s  += sLN[w ^ 4][r31][0];                    // pair wave = nh flip
        s2 += sLN[w ^ 4][r31][1];
        float mean = s * (1.0f / 128.0f);
        float rsv  = rsqrtf(s2 * (1.0f / 128.0f) - mean * mean + 1e-5f);
#pragma unroll
        for (int f = 0; f < 2; f++)
#pragma unroll
            for (int q = 0; q < 4; q++) {
                f32x4 b4 = *(const f32x4*)(bb + nh * 64 + f * 32 + q * 8 + l5 * 4);
                f32x4 g4 = *(const f32x4*)(gg + nh * 64 + f * 32 + q * 8 + l5 * 4);
                f32x4 e4 = *(const f32x4*)(ee + nh * 64 + f * 32 + q * 8 + l5 * 4);
                bf16x4 u;
#pragma unroll
                for (int j = 0; j < 4; j++) {
                    float v = acc[f][q * 4 + j] + b4[j];
                    float fv = (v - mean) * rsv * g4[j] + e4[j];
                    u[j] = (__bf16)gelu_t(fv);       // v_cvt_pk_bf16_f32 (RNE)
                }
                // byte = 2n = nh*128 + f*64 + q*16 + l5*8
                *(bf16x4*)(sA + eloc * 256 +
                           ((nh * 128 + f * 64 + q * 16 + l5 * 8) ^ swzl)) = u;
            }
    };

    // ---- layer-3 GEMV: o = c*4 + 2nh + f, i = 8q + 4*l5 + j; b3 folded;
    //      owner half-wave (c>>2 == l5) stores float2 directly. ----
    f32x4 xv[4];                      // xv[q][j] = x[eloc][8q + 4*l5 + j]
    auto gemv = [&](f32x16 (&acc)[2], int c) {       // c compile-time const
        float pf[2];
#pragma unroll
        for (int f = 0; f < 2; f++) {
            float p = 0.f;
#pragma unroll
            for (int q = 0; q < 4; q++) {
                f32x4 b4 = *(const f32x4*)(
                    b3 + c * 128 + nh * 64 + f * 32 + q * 8 + l5 * 4);
#pragma unroll
                for (int j = 0; j < 4; j++)
                    p += (acc[f][q * 4 + j] + b4[j]) * xv[q][j];
            }
            p += __shfl_xor(p, 32);                  // other i-half
            pf[f] = p;
        }
        if ((c >> 2) == l5) {                        // owner half-wave stores
            float2 pv = {pf[0], pf[1]};
            *(float2*)(out + (size_t)(e0 + eloc) * 32 + c * 4 + 2 * nh) = pv;
        }
    };

    // ================= prologue =================
    stageW(wsW, sW);                                 // W1 DMA (overlaps below)
#pragma unroll
    for (int i = 0; i < 4; i++) {                    // edge -> sA (R10 verbatim)
        int c = lane + i * 64;                       // 256 chunks of 8 floats
        int r = erow + (c >> 4), kg = c & 15;
        const float* src = edge + (size_t)(e0 + r) * 128 + kg * 8;
        float4 v0 = *(const float4*)src, v1 = *(const float4*)(src + 4);
        bf16x8 u;
        u[0] = (__bf16)v0.x; u[1] = (__bf16)v0.y; u[2] = (__bf16)v0.z; u[3] = (__bf16)v0.w;
        u[4] = (__bf16)v1.x; u[5] = (__bf16)v1.y; u[6] = (__bf16)v1.z; u[7] = (__bf16)v1.w;
        *(bf16x8*)(sA + r * 256 + ((kg * 16) ^ ((r & 7) << 4))) = u;
    }
#pragma unroll
    for (int q = 0; q < 4; q++)
        xv[q] = *(const f32x4*)(x + (size_t)(e0 + eloc) * 32 + q * 8 + l5 * 4);
    __syncthreads();                                 // W1 in LDS

    f32x16 acc[2];
    float s, s2;

    // ================= layer 1 =================
    runMM(acc);                       // reads sW(W1) + sA(edge)
    lnPart(acc, b1, s, s2);           // partials -> sLN
    __syncthreads();                  // (a) sW free, sLN visible
    stageW(wsW + 16384, sW);          // W2 DMA (overlaps lnFinish VALU)
    lnFinish(acc, b1, g1, be1, s, s2);// h1 -> sA (pair-disjoint bytes)
    __syncthreads();                  // (b) W2 ready, h1 visible

    // ================= layer 2 =================
    runMM(acc);
    lnPart(acc, b2, s, s2);
    __syncthreads();                  // (c)
    stageW(wsW + 32768, sW);          // W3 chunk 0 DMA
    lnFinish(acc, b2, g2, be2, s, s2);// h2 -> sA
    __syncthreads();                  // (d) W3c0 ready, h2 visible

    // ---- cache h2 B-frags (own eg, full K) in regs ----
    bf16x8 bc[8];
#pragma unroll
    for (int ks = 0; ks < 8; ks++)
        bc[ks] = *(const bf16x8*)(sA + eloc * 256 + ((ks * 32 + l5 * 16) ^ swzl));
    __syncthreads();                  // (e) bc reads done -> sA free
    stageW(wsW + 32768 + 16384, sA);  // W3 chunk 1 DMA -> sA

    // ================= layer 3: 8 chunks, ping-pong sW/sA =================
#pragma unroll
    for (int c = 0; c < 8; c++) {
        runMM3(acc, bc, (c & 1) ? sA : sW);   // read current buffer
        gemv(acc, c);                         // R10 position (R14: moving hurts)
        if (c < 7) {
            __syncthreads();          // buf(c&1) reads done; DMA(c+1) drained
            if (c < 6)                // DMA c+2 into the buffer just freed
                stageW(wsW + 32768 + (size_t)(c + 2) * 16384,
                       (c & 1) ? sA : sW);
        }
    }
}

extern "C" void kernel_launch(void* const* d_in, const int* in_sizes, int n_in,
                              void* d_out, int out_size, void* d_ws, size_t ws_size,
                              hipStream_t stream) {
    const float* x    = (const float*)d_in[0];
    const float* edge = (const float*)d_in[1];
    const float* W1   = (const float*)d_in[2];
    const float* b1   = (const float*)d_in[3];
    const float* g1   = (const float*)d_in[4];
    const float* be1  = (const float*)d_in[5];
    const float* W2   = (const float*)d_in[6];
    const float* b2   = (const float*)d_in[7];
    const float* g2   = (const float*)d_in[8];
    const float* be2  = (const float*)d_in[9];
    const float* W3   = (const float*)d_in[10];
    const float* b3   = (const float*)d_in[11];
    unsigned short* wsW = (unsigned short*)d_ws;     // 320 KB pre-swizzled W^T bf16
    float* outp = (float*)d_out;

    prep_weights<<<640, 256, 0, stream>>>(W1, W2, W3, wsW);
    fused_edge_mlp<<<N_EDGES / TM, NTHR, 0, stream>>>(
        edge, x, b1, g1, be1, b2, g2, be2, b3, wsW, outp);
}